// Round 2
// baseline (351.509 us; speedup 1.0000x reference)
//
#include <hip/hip_runtime.h>

#define NK 512
#define ND 64
#define NHW 4096
#define NPIX 131072            // 32*64*64
#define OUT_ELEMS 8388608      // 32*64*64*64
#define NGROUPS 64             // 64 groups x 8 codes = 512
#define GSTRIDE 528            // floats/group: 512 transposed data + 8 sc + 8 pad

typedef float f16v __attribute__((ext_vector_type(16)));

// Transposed codebook table, built by vq_prep each launch (stream-ordered
// before vq_main; module global is not re-poisoned by the harness, but we
// rewrite it every launch anyway).
// Layout per group g (8 codes k=8g+c), 64B-aligned blocks:
//   cbt[g*528 + dq*32 + c*4 + q] = cb[(8g+c)*64 + dq*4 + q]   (dq=0..15)
//   cbt[g*528 + 512 + c]         = sc[8g+c]  (pairwise-8 sum of squares)
__device__ __attribute__((aligned(64))) float cbt[NGROUPS * GSTRIDE];

// ---------------------------------------------------------------------------
// Prep: transpose codebook into cbt + sc (numpy-pairwise-8 fp32 sum of
// fl(c_d^2)); zero the two loss slots (harness re-poisons d_out/d_ws to
// 0xAA before every timed replay).
// ---------------------------------------------------------------------------
__global__ __launch_bounds__(256) void vq_prep(const float* __restrict__ cb,
                                               float* __restrict__ losses) {
#pragma clang fp contract(off)
  {
    const int k = blockIdx.x * 256 + threadIdx.x;   // grid 2*256 = 512
    const float* c = cb + (size_t)k * ND;
    const int g = k >> 3, cc = k & 7;
    float* gb = cbt + (size_t)g * GSTRIDE;

    float4 v[16];
#pragma unroll
    for (int dq = 0; dq < 16; ++dq) {
      v[dq] = *(const float4*)(c + dq * 4);
      *(float4*)(gb + dq * 32 + cc * 4) = v[dq];
    }
    // Pairwise-8 sum of rounded squares: r[j] = sum_i q[8i+j] (bitwise = R2).
    float rr[8];
    rr[0] = v[0].x * v[0].x; rr[1] = v[0].y * v[0].y; rr[2] = v[0].z * v[0].z; rr[3] = v[0].w * v[0].w;
    rr[4] = v[1].x * v[1].x; rr[5] = v[1].y * v[1].y; rr[6] = v[1].z * v[1].z; rr[7] = v[1].w * v[1].w;
#pragma unroll
    for (int i = 2; i < 16; i += 2) {
      rr[0] += v[i].x * v[i].x;     rr[1] += v[i].y * v[i].y;
      rr[2] += v[i].z * v[i].z;     rr[3] += v[i].w * v[i].w;
      rr[4] += v[i + 1].x * v[i + 1].x; rr[5] += v[i + 1].y * v[i + 1].y;
      rr[6] += v[i + 1].z * v[i + 1].z; rr[7] += v[i + 1].w * v[i + 1].w;
    }
    gb[512 + cc] = ((rr[0] + rr[1]) + (rr[2] + rr[3])) + ((rr[4] + rr[5]) + (rr[6] + rr[7]));
    if (k < 2) losses[k] = 0.f;
  }
}

// ---------------------------------------------------------------------------
// Main: lane = pixel. x[64] lives in VGPRs (constant-indexed, fully
// unrolled). Codebook comes in via wave-uniform 64B loads of cbt (compiler
// scalarizes to s_load_dwordx16 / uniform VMEM — either way the K-loop uses
// NO LDS, NO barriers, NO cross-lane ops). R2 theory: R1 was
// LDS<->VALU serialization-bound at 2 waves/SIMD (VALUBusy 54% + LDS ~50%
// ~= sum, not max); pure-VALU loop floor is 54.6us + ~10% overhead.
// Numerics bit-identical to passing R2/R5/R7/R9/R1: per-(n,k) sequential
// fp32 FMA chain d=0..63 (dq ascending, xyzw within quad); d2 = fl(fl(Sx -
// fl(2M)) + Sc); Sx/sc numpy pairwise-8 of rounded squares; candidates
// ascend in code (c then g) with strict '<' => lowest index wins ties =
// np.argmin (fully in-lane, no cross-lane tie-break needed).
// ---------------------------------------------------------------------------
__global__ __launch_bounds__(256, 2) void vq_main(const float* __restrict__ x,
                                                  const float* __restrict__ cb,
                                                  float* __restrict__ out,
                                                  float* __restrict__ idx_out,
                                                  float* __restrict__ losses) {
#pragma clang fp contract(off)
  {
    __shared__ float red[4];

    const int tid = threadIdx.x;
    const int px = blockIdx.x * 256 + tid;    // grid 512*256 = 131072
    const int b = px >> 12;
    const int hw = px & 4095;
    const float* xp = x + (size_t)b * (ND * NHW) + hw;

    // ---- x into registers: 64 coalesced dword loads (lane i -> hw+i).
    float xr[ND];
#pragma unroll
    for (int d = 0; d < ND; ++d) xr[d] = xp[(size_t)d * NHW];

    // ---- Sx: rounded squares, pairwise-8 (bitwise = R2).
    float rr[8];
    rr[0] = xr[0] * xr[0]; rr[1] = xr[1] * xr[1]; rr[2] = xr[2] * xr[2]; rr[3] = xr[3] * xr[3];
    rr[4] = xr[4] * xr[4]; rr[5] = xr[5] * xr[5]; rr[6] = xr[6] * xr[6]; rr[7] = xr[7] * xr[7];
#pragma unroll
    for (int i = 2; i < 16; i += 2) {
      rr[0] += xr[i * 4 + 0] * xr[i * 4 + 0]; rr[1] += xr[i * 4 + 1] * xr[i * 4 + 1];
      rr[2] += xr[i * 4 + 2] * xr[i * 4 + 2]; rr[3] += xr[i * 4 + 3] * xr[i * 4 + 3];
      rr[4] += xr[i * 4 + 4] * xr[i * 4 + 4]; rr[5] += xr[i * 4 + 5] * xr[i * 4 + 5];
      rr[6] += xr[i * 4 + 6] * xr[i * 4 + 6]; rr[7] += xr[i * 4 + 7] * xr[i * 4 + 7];
    }
    const float Sx = ((rr[0] + rr[1]) + (rr[2] + rr[3])) + ((rr[4] + rr[5]) + (rr[6] + rr[7]));

    // ---- K loop: 64 groups x 8 codes; 8 independent FMA chains.
    float m = 3.0e38f;
    int best = 0;
    for (int g = 0; g < NGROUPS; ++g) {
      const float* gb = cbt + (size_t)g * GSTRIDE;
      float a0 = 0.f, a1 = 0.f, a2 = 0.f, a3 = 0.f;
      float a4 = 0.f, a5 = 0.f, a6 = 0.f, a7 = 0.f;
#pragma unroll
      for (int dq = 0; dq < 16; ++dq) {
        const f16v ta = *(const f16v*)(gb + dq * 32);        // codes 8g+0..3
        const f16v tb = *(const f16v*)(gb + dq * 32 + 16);   // codes 8g+4..7
        const float x0 = xr[dq * 4 + 0], x1 = xr[dq * 4 + 1];
        const float x2 = xr[dq * 4 + 2], x3 = xr[dq * 4 + 3];
#define VQ_CH(A, T, BASE)                                  \
        A = __builtin_fmaf(T[BASE + 0], x0, A);            \
        A = __builtin_fmaf(T[BASE + 1], x1, A);            \
        A = __builtin_fmaf(T[BASE + 2], x2, A);            \
        A = __builtin_fmaf(T[BASE + 3], x3, A);
        VQ_CH(a0, ta, 0) VQ_CH(a1, ta, 4) VQ_CH(a2, ta, 8) VQ_CH(a3, ta, 12)
        VQ_CH(a4, tb, 0) VQ_CH(a5, tb, 4) VQ_CH(a6, tb, 8) VQ_CH(a7, tb, 12)
#undef VQ_CH
      }
      // Combine + running argmin (codes ascend c=0..7 then groups).
      const int kb = g << 3;
      float d2;
      d2 = (Sx - 2.0f * a0) + gb[512 + 0]; if (d2 < m) { m = d2; best = kb + 0; }
      d2 = (Sx - 2.0f * a1) + gb[512 + 1]; if (d2 < m) { m = d2; best = kb + 1; }
      d2 = (Sx - 2.0f * a2) + gb[512 + 2]; if (d2 < m) { m = d2; best = kb + 2; }
      d2 = (Sx - 2.0f * a3) + gb[512 + 3]; if (d2 < m) { m = d2; best = kb + 3; }
      d2 = (Sx - 2.0f * a4) + gb[512 + 4]; if (d2 < m) { m = d2; best = kb + 4; }
      d2 = (Sx - 2.0f * a5) + gb[512 + 5]; if (d2 < m) { m = d2; best = kb + 5; }
      d2 = (Sx - 2.0f * a6) + gb[512 + 6]; if (d2 < m) { m = d2; best = kb + 6; }
      d2 = (Sx - 2.0f * a7) + gb[512 + 7]; if (d2 < m) { m = d2; best = kb + 7; }
    }

    // ---- Epilogue: gather winning row, write out (coalesced dword stores),
    // accumulate loss in-lane then wave/block reduce.
    idx_out[px] = (float)best;
    const float* qrow = cb + (size_t)best * ND;
    float* op = out + (size_t)b * (ND * NHW) + hw;
    float lossp = 0.f;
#pragma unroll
    for (int dq = 0; dq < 16; ++dq) {
      const float4 q = *(const float4*)(qrow + dq * 4);
      float e;
      e = xr[dq * 4 + 0] - q.x; lossp = __builtin_fmaf(e, e, lossp); op[(size_t)(dq * 4 + 0) * NHW] = q.x;
      e = xr[dq * 4 + 1] - q.y; lossp = __builtin_fmaf(e, e, lossp); op[(size_t)(dq * 4 + 1) * NHW] = q.y;
      e = xr[dq * 4 + 2] - q.z; lossp = __builtin_fmaf(e, e, lossp); op[(size_t)(dq * 4 + 2) * NHW] = q.z;
      e = xr[dq * 4 + 3] - q.w; lossp = __builtin_fmaf(e, e, lossp); op[(size_t)(dq * 4 + 3) * NHW] = q.w;
    }
#pragma unroll
    for (int off = 32; off; off >>= 1) lossp += __shfl_down(lossp, off);
    const int wv = tid >> 6, lane = tid & 63;
    if (lane == 0) red[wv] = lossp;
    __syncthreads();
    if (tid == 0) {
      float t = (red[0] + red[1] + red[2] + red[3]) * (1.f / 8388608.f);
      atomicAdd(losses + 0, t);   // dictionary_loss
      atomicAdd(losses + 1, t);   // commitment_loss (identical forward value)
    }
  }
}

extern "C" void kernel_launch(void* const* d_in, const int* in_sizes, int n_in,
                              void* d_out, int out_size, void* d_ws, size_t ws_size,
                              hipStream_t stream) {
  const float* x  = (const float*)d_in[0];   // [32,64,64,64] fp32
  const float* cb = (const float*)d_in[1];   // [512,64] fp32
  float* out     = (float*)d_out;            // quantized [B,D,H,W]
  float* idx_out = out + OUT_ELEMS;          // indices (as fp32) [B,H,W]
  float* losses  = idx_out + NPIX;           // 2 scalars
  (void)d_ws; (void)ws_size;                 // workspace no longer needed

  vq_prep<<<2, 256, 0, stream>>>(cb, losses);
  vq_main<<<NPIX / 256, 256, 0, stream>>>(x, cb, out, idx_out, losses);
}

// Round 4
// 250.093 us; speedup vs baseline: 1.4055x; 1.4055x over previous
//
#include <hip/hip_runtime.h>

#define NK 512
#define ND 64
#define NHW 4096
#define NPIX 131072            // 32*64*64
#define OUT_ELEMS 8388608      // 32*64*64*64

typedef float f4  __attribute__((ext_vector_type(4)));
typedef float f16 __attribute__((ext_vector_type(16)));

// ---------------------------------------------------------------------------
// Prep: sc[k] = numpy-pairwise-8 fp32 sum of fl(c_d^2) into d_ws; zero the
// two loss slots (harness re-poisons d_out/d_ws to 0xAA every replay).
// ---------------------------------------------------------------------------
__global__ __launch_bounds__(256) void vq_prep(const float* __restrict__ cb,
                                               float* __restrict__ sc,
                                               float* __restrict__ losses) {
#pragma clang fp contract(off)
  {
    int k = blockIdx.x * 256 + threadIdx.x;   // grid 2*256 = 512
    const float* c = cb + (size_t)k * ND;
    float q[ND];
#pragma unroll
    for (int d = 0; d < ND; ++d) q[d] = c[d] * c[d];
    float r[8];
#pragma unroll
    for (int j = 0; j < 8; ++j) r[j] = q[j];
#pragma unroll
    for (int i = 8; i < ND; i += 8)
#pragma unroll
      for (int j = 0; j < 8; ++j) r[j] += q[i + j];
    sc[k] = ((r[0] + r[1]) + (r[2] + r[3])) + ((r[4] + r[5]) + (r[6] + r[7]));
    if (k < 2) losses[k] = 0.f;
  }
}

// ---------------------------------------------------------------------------
// Main: lane = pixel; codebook streamed through SGPRs via explicit
// s_load_dwordx16. R3 failed to compile because the address operand was
// divergence-classified (derived from threadIdx) and clang emitted a VGPR
// pair into the SMEM instruction; fix: launder the wave-uniform base through
// readfirstlane (lo/hi) so uniformity is provable and the "s" constraint
// allocates a real SGPR pair. Half-code granularity: 32 floats = 2 loads =
// 32 SGPRs, A/B rotate = 64 SGPRs live (fits ~102 budget; R2's failure
// needed 128+ which forced codebook into VGPRs and spilled x). x lives in
// 16 named f4 registers. K is split: waves 0,1 -> codes 0..255, waves 2,3
// -> 256..511 for the same 128 pixels; grid 1024 blocks = 4 blocks/CU =
// 4 waves/SIMD, so 4 half-duty dependent FMA chains saturate VALU issue.
// Numerics bit-identical to all passing versions: per-(n,k) sequential fp32
// FMA chain d=0..63 (dq ascending, component order within quad); d2 =
// fl(fl(Sx - fl(2a)) + Sc) (2a exact in fp32); Sx/sc numpy pairwise-8 of
// rounded squares; candidates ascend in code with strict '<'; cross-half
// tie keeps low half => lowest index wins = np.argmin.
// ---------------------------------------------------------------------------
__global__ __launch_bounds__(256, 4) void vq_main(const float* __restrict__ x,
                                                  const float* __restrict__ cb,
                                                  const float* __restrict__ sc,
                                                  float* __restrict__ out,
                                                  float* __restrict__ idx_out,
                                                  float* __restrict__ losses) {
#pragma clang fp contract(off)
  {
    __shared__ float him[128];
    __shared__ int   hii[128];
    __shared__ float red[2];

    const int tid = threadIdx.x;
    const int wv = tid >> 6;                 // 0..3
    const int lane = tid & 63;
    const int pxl = ((wv & 1) << 6) | lane;  // local pixel 0..127
    const int px = blockIdx.x * 128 + pxl;
    const int b = px >> 12;
    const int hw = px & 4095;
    const float* xp = x + (size_t)b * (ND * NHW) + hw;

    // ---- x into 16 named f4 registers (coalesced dword loads).
    f4 xv0, xv1, xv2, xv3, xv4, xv5, xv6, xv7;
    f4 xv8, xv9, xv10, xv11, xv12, xv13, xv14, xv15;
#define LX(V, D)                           \
    V[0] = xp[(size_t)(D + 0) * NHW];      \
    V[1] = xp[(size_t)(D + 1) * NHW];      \
    V[2] = xp[(size_t)(D + 2) * NHW];      \
    V[3] = xp[(size_t)(D + 3) * NHW];
    LX(xv0, 0)  LX(xv1, 4)  LX(xv2, 8)   LX(xv3, 12)
    LX(xv4, 16) LX(xv5, 20) LX(xv6, 24)  LX(xv7, 28)
    LX(xv8, 32) LX(xv9, 36) LX(xv10, 40) LX(xv11, 44)
    LX(xv12, 48) LX(xv13, 52) LX(xv14, 56) LX(xv15, 60)
#undef LX

    // ---- Sx: rounded squares, pairwise-8 (bitwise = prior rounds).
    float rr0 = xv0[0] * xv0[0], rr1 = xv0[1] * xv0[1];
    float rr2 = xv0[2] * xv0[2], rr3 = xv0[3] * xv0[3];
    float rr4 = xv1[0] * xv1[0], rr5 = xv1[1] * xv1[1];
    float rr6 = xv1[2] * xv1[2], rr7 = xv1[3] * xv1[3];
#define SXA(E, O)                                          \
    rr0 += E[0] * E[0]; rr1 += E[1] * E[1];                \
    rr2 += E[2] * E[2]; rr3 += E[3] * E[3];                \
    rr4 += O[0] * O[0]; rr5 += O[1] * O[1];                \
    rr6 += O[2] * O[2]; rr7 += O[3] * O[3];
    SXA(xv2, xv3) SXA(xv4, xv5) SXA(xv6, xv7)
    SXA(xv8, xv9) SXA(xv10, xv11) SXA(xv12, xv13) SXA(xv14, xv15)
#undef SXA
    const float Sx = ((rr0 + rr1) + (rr2 + rr3)) + ((rr4 + rr5) + (rr6 + rr7));

    // ---- K loop: this wave's 256 codes via SGPR half-code streaming.
    const int k0 = (wv >> 1) << 8;                  // 0 or 256 (wave-uniform)
    const float* scu = sc + k0;

    // Launder the wave-uniform codebook base into the scalar domain.
    const unsigned long long baddr =
        (unsigned long long)(const void*)(cb + (size_t)k0 * ND);
    const unsigned int blo = __builtin_amdgcn_readfirstlane((unsigned int)baddr);
    const unsigned int bhi = __builtin_amdgcn_readfirstlane((unsigned int)(baddr >> 32));
    const unsigned long long base = ((unsigned long long)bhi << 32) | blo;

    f16 A0, A1, B0, B1;
    // Prologue: A <- dims 0..31 of code 0.
    asm volatile("s_load_dwordx16 %0, %2, 0x0\n\t"
                 "s_load_dwordx16 %1, %2, 0x40"
                 : "=s"(A0), "=s"(A1) : "s"(base));
    asm volatile("s_waitcnt lgkmcnt(0)" : "+s"(A0), "+s"(A1));
    __builtin_amdgcn_sched_barrier(0);

    float m = 3.0e38f;
    int best = 0;

#define FMA16(T, Q0, Q1, Q2, Q3)                                \
    a = __builtin_fmaf(T[0],  Q0[0], a);                        \
    a = __builtin_fmaf(T[1],  Q0[1], a);                        \
    a = __builtin_fmaf(T[2],  Q0[2], a);                        \
    a = __builtin_fmaf(T[3],  Q0[3], a);                        \
    a = __builtin_fmaf(T[4],  Q1[0], a);                        \
    a = __builtin_fmaf(T[5],  Q1[1], a);                        \
    a = __builtin_fmaf(T[6],  Q1[2], a);                        \
    a = __builtin_fmaf(T[7],  Q1[3], a);                        \
    a = __builtin_fmaf(T[8],  Q2[0], a);                        \
    a = __builtin_fmaf(T[9],  Q2[1], a);                        \
    a = __builtin_fmaf(T[10], Q2[2], a);                        \
    a = __builtin_fmaf(T[11], Q2[3], a);                        \
    a = __builtin_fmaf(T[12], Q3[0], a);                        \
    a = __builtin_fmaf(T[13], Q3[1], a);                        \
    a = __builtin_fmaf(T[14], Q3[2], a);                        \
    a = __builtin_fmaf(T[15], Q3[3], a);

#define VQ_CODE(U, SCQC)                                                      \
    {                                                                         \
      const int kk = q4 + U;                                                  \
      const unsigned long long ca = base + ((unsigned long long)kk << 8);     \
      /* issue B <- dims 32..63 of code kk */                                 \
      asm volatile("s_load_dwordx16 %0, %2, 0x80\n\t"                         \
                   "s_load_dwordx16 %1, %2, 0xc0"                             \
                   : "=s"(B0), "=s"(B1) : "s"(ca));                           \
      float a = 0.f;                                                          \
      FMA16(A0, xv0, xv1, xv2, xv3)        /* dims 0..15  */                  \
      FMA16(A1, xv4, xv5, xv6, xv7)        /* dims 16..31 */                  \
      asm volatile("s_waitcnt lgkmcnt(0)" : "+s"(B0), "+s"(B1));              \
      __builtin_amdgcn_sched_barrier(0);                                      \
      /* issue A <- dims 0..31 of next code (clamped, uniform) */             \
      const unsigned long long cn =                                           \
          base + ((unsigned long long)((kk < 255) ? kk + 1 : 255) << 8);      \
      asm volatile("s_load_dwordx16 %0, %2, 0x0\n\t"                          \
                   "s_load_dwordx16 %1, %2, 0x40"                             \
                   : "=s"(A0), "=s"(A1) : "s"(cn));                           \
      FMA16(B0, xv8, xv9, xv10, xv11)      /* dims 32..47 */                  \
      FMA16(B1, xv12, xv13, xv14, xv15)    /* dims 48..63 */                  \
      const float d2 = (Sx - 2.0f * a) + SCQC;                                \
      if (d2 < m) { m = d2; best = k0 + kk; }                                 \
      asm volatile("s_waitcnt lgkmcnt(0)" : "+s"(A0), "+s"(A1));              \
      __builtin_amdgcn_sched_barrier(0);                                      \
    }

    for (int q = 0; q < 64; ++q) {
      const int q4 = q * 4;
      const f4 scq = *(const f4*)(scu + q4);   // uniform values, tiny load
      VQ_CODE(0, scq[0])
      VQ_CODE(1, scq[1])
      VQ_CODE(2, scq[2])
      VQ_CODE(3, scq[3])
    }
#undef VQ_CODE
#undef FMA16

    // ---- Cross-half argmin: high half (waves 2,3) publishes; low half
    // combines with strict '<' (tie keeps low half's lower index).
    if (wv >= 2) { him[pxl] = m; hii[pxl] = best; }
    __syncthreads();

    float lossp = 0.f;
    if (wv < 2) {
      const float mh = him[pxl];
      const int ih = hii[pxl];
      if (mh < m) { m = mh; best = ih; }
      idx_out[px] = (float)best;
      const float* qrow = cb + (size_t)best * ND;
      float* op = out + (size_t)b * (ND * NHW) + hw;
#define EPI(Q, D)                                                             \
      {                                                                       \
        const f4 qv = *(const f4*)(qrow + D);                                 \
        float e;                                                              \
        e = Q[0] - qv[0]; lossp = __builtin_fmaf(e, e, lossp); op[(size_t)(D + 0) * NHW] = qv[0]; \
        e = Q[1] - qv[1]; lossp = __builtin_fmaf(e, e, lossp); op[(size_t)(D + 1) * NHW] = qv[1]; \
        e = Q[2] - qv[2]; lossp = __builtin_fmaf(e, e, lossp); op[(size_t)(D + 2) * NHW] = qv[2]; \
        e = Q[3] - qv[3]; lossp = __builtin_fmaf(e, e, lossp); op[(size_t)(D + 3) * NHW] = qv[3]; \
      }
      EPI(xv0, 0)  EPI(xv1, 4)  EPI(xv2, 8)   EPI(xv3, 12)
      EPI(xv4, 16) EPI(xv5, 20) EPI(xv6, 24)  EPI(xv7, 28)
      EPI(xv8, 32) EPI(xv9, 36) EPI(xv10, 40) EPI(xv11, 44)
      EPI(xv12, 48) EPI(xv13, 52) EPI(xv14, 56) EPI(xv15, 60)
#undef EPI
    }
#pragma unroll
    for (int off = 32; off; off >>= 1) lossp += __shfl_down(lossp, off);
    if (lane == 0 && wv < 2) red[wv] = lossp;
    __syncthreads();
    if (tid == 0) {
      float t = (red[0] + red[1]) * (1.f / 8388608.f);
      atomicAdd(losses + 0, t);   // dictionary_loss
      atomicAdd(losses + 1, t);   // commitment_loss (identical forward value)
    }
  }
}

extern "C" void kernel_launch(void* const* d_in, const int* in_sizes, int n_in,
                              void* d_out, int out_size, void* d_ws, size_t ws_size,
                              hipStream_t stream) {
  const float* x  = (const float*)d_in[0];   // [32,64,64,64] fp32
  const float* cb = (const float*)d_in[1];   // [512,64] fp32
  float* out     = (float*)d_out;            // quantized [B,D,H,W]
  float* idx_out = out + OUT_ELEMS;          // indices (as fp32) [B,H,W]
  float* losses  = idx_out + NPIX;           // 2 scalars
  float* sc      = (float*)d_ws;             // 512 floats scratch

  vq_prep<<<2, 256, 0, stream>>>(cb, sc, losses);
  vq_main<<<NPIX / 128, 256, 0, stream>>>(x, cb, sc, out, idx_out, losses);
}